// Round 7
// baseline (354.709 us; speedup 1.0000x reference)
//
#include <hip/hip_runtime.h>
#include <math.h>
#include <stdint.h>

#define TOK 65536
#define DIN 256
#define EDIM 512
#define KCB 2048
#define NTB 128         // B n-tiles (2048/16)

// workspace layout (float offsets), 64-float aligned
#define OFF_MP   0u                     // (unused after fusion; kept for layout stability)
#define OFF_CP   524288u                // c' [2048]
#define OFF_Q    526336u                // Q [2048*256]
#define OFF_W2T  1050624u               // W2T [512*256]
#define OFF_U    1181696u               // u [512]
#define OFF_CQ   1182208u               // cQ [256]
#define OFF_BH   1182464u               // B packed bf16 [8][128][512]
#define TOT_F    1444608u

typedef short short8 __attribute__((ext_vector_type(8)));
typedef float f32x4 __attribute__((ext_vector_type(4)));

__device__ __forceinline__ unsigned short bf16rne(float x) {
    uint32_t u = __float_as_uint(x);
    u += 0x7fffu + ((u >> 16) & 1u);
    return (unsigned short)(u >> 16);
}

// fused: zero loss scalar + usage bins, then W2T / u / cQ.
// blocks 0..511: e -> W2T[e][o], u[e];  512..767: o -> cQ[o]
__global__ void prep1_kernel(const float* __restrict__ W1, const float* __restrict__ W2,
                             const float* __restrict__ bn1_beta, const float* __restrict__ bn2_gamma,
                             const float* __restrict__ bn2_beta, const float* __restrict__ b2,
                             float* __restrict__ W2T, float* __restrict__ u, float* __restrict__ cQ,
                             float* __restrict__ out) {
    __shared__ float red[256];
    const int b = blockIdx.x, t = threadIdx.x;
    const int gid = b * 256 + t;
    if (gid == 0) out[0] = 0.0f;
    if (gid < KCB) out[1 + TOK * DIN + gid] = 0.0f;
    const float s = 1.0f / sqrtf(1.0f + 1e-5f);
    if (b < EDIM) {
        int e = b;
        W2T[e * DIN + t] = bn2_gamma[e] * s * W2[t * EDIM + e];
        float v = bn1_beta[t] * W1[e * DIN + t];
        red[t] = v; __syncthreads();
        for (int off = 128; off; off >>= 1) { if (t < off) red[t] += red[t + off]; __syncthreads(); }
        if (t == 0) u[e] = red[0];
    } else {
        int o = b - EDIM;
        float v = bn2_beta[t] * W2[o * EDIM + t] + bn2_beta[t + 256] * W2[o * EDIM + t + 256];
        red[t] = v; __syncthreads();
        for (int off = 128; off; off >>= 1) { if (t < off) red[t] += red[t + off]; __syncthreads(); }
        if (t == 0) cQ[o] = b2[o] + red[0];
    }
}

// FUSED prep2+packB: 256 blocks x 512 threads; 8 codebook rows per block
// (half h = t>>8 owns rows h*4..h*4+3, col = t&255).
// Broadcast operand E read via wave-uniform SCALAR loads (SMEM path).
// Outputs: Q (fp32), cp, and Bh bf16 MFMA fragments DIRECTLY.
__global__ __launch_bounds__(512) void prep2_kernel(const float* __restrict__ E, const float* __restrict__ W1,
                                                    const float* __restrict__ W2T, const float* __restrict__ bn1_gamma,
                                                    const float* __restrict__ cQ, const float* __restrict__ b1,
                                                    const float* __restrict__ u,
                                                    float* __restrict__ Q, float* __restrict__ cp,
                                                    unsigned short* __restrict__ Bh) {
    __shared__ __align__(16) unsigned short hs[8][264];   // bf16 of Mp rows, padded
    const int t = threadIdx.x;
    const int col = t & 255;
    const int half = __builtin_amdgcn_readfirstlane(t >> 8);   // wave-uniform 0/1
    const int k0 = blockIdx.x * 8;
    const float* __restrict__ Ek = E + ((size_t)k0 + (size_t)half * 4) * EDIM;

    float m[4] = {0, 0, 0, 0};
    float q[4] = {0, 0, 0, 0};
    for (int e0 = 0; e0 < EDIM; e0 += 8) {
        float w1v[8], w2v[8];
#pragma unroll
        for (int j = 0; j < 8; j++) {
            w1v[j] = W1[(e0 + j) * DIN + col];
            w2v[j] = W2T[(e0 + j) * DIN + col];
        }
#pragma unroll
        for (int r = 0; r < 4; r++) {
#pragma unroll
            for (int j = 0; j < 8; j++) {
                float ev = Ek[(size_t)r * EDIM + e0 + j];   // uniform -> s_load
                m[r] += ev * w1v[j];
                q[r] += ev * w2v[j];
            }
        }
    }
    const float s = 1.0f / sqrtf(1.0f + 1e-5f);
    const float gs = bn1_gamma[col] * s;
    const float cq = cQ[col];
#pragma unroll
    for (int r = 0; r < 4; r++) {
        Q[(size_t)(k0 + half * 4 + r) * DIN + col] = q[r] + cq;
        hs[half * 4 + r][col] = bf16rne(gs * m[r]);
    }

    // fused prep3: c'[k0+wv] = E[k]·(b1+u) - 0.5*||E[k]||², one wave per row
    {
        const int wv = t >> 6, l = t & 63;
        const float* __restrict__ Er = E + (size_t)(k0 + wv) * EDIM;
        float sa = 0.0f, sb = 0.0f;
#pragma unroll
        for (int i = 0; i < 8; i++) {
            int e = l + i * 64;
            float ev = Er[e];
            float be = b1[e] + u[e];
            sa += ev * be; sb += ev * ev;
        }
        float v = sa - 0.5f * sb;
#pragma unroll
        for (int off = 32; off; off >>= 1) v += __shfl_down(v, off, 64);
        if (l == 0) cp[k0 + wv] = v;
    }

    __syncthreads();   // hs complete

    // Bh fragment write: 256 chunks of 16B (8 rows x 8 kc x 4 qr), threads t<256.
    if (t < 256) {
        const int rr = t & 7, qr = (t >> 3) & 3, kc = t >> 5;
        const int nt = k0 >> 4;
        const int l2 = (k0 & 8) + rr + (qr << 4);
        short8 vh = *(const short8*)&hs[rr][kc * 32 + qr * 8];
        *(short8*)&Bh[((size_t)kc * NTB + nt) * 512 + (size_t)l2 * 8] = vh;
    }
}

// MEGA-KERNEL v7: independent-wave streaming scorer, 4 waves/SIMD.
// R6 showed structure-invariant ~135 µs at 2 waves/SIMD (MfmaUtil 20%);
// the untested cell is {high occupancy x no barriers}. Here each wave owns
// 16 rows x ALL 2048 codes: af[8]=32 VGPR, one acc chain, total ~105 regs
// -> 4 waves/SIMD under launch_bounds(256,4). Grid 1024 x 4 waves = 4096
// waves. ZERO __syncthreads: argmax never crosses waves; gather uses static
// __shfl broadcast (no LDS). All waves read the same B stream in the same
// order -> L1 dedup bounds L2 traffic. Score chain identical -> bit-exact.
__global__ __launch_bounds__(256, 4) void score_fused_kernel(const float* __restrict__ flat,
                                                             const unsigned short* __restrict__ Bh,
                                                             const float* __restrict__ cp,
                                                             const float* __restrict__ Q,
                                                             float* __restrict__ out) {
    const int t = threadIdx.x, lane = t & 63, w = t >> 6;   // w = 0..3
    const int m0 = blockIdx.x * 64;
    const int fr = lane & 15, qr = lane >> 4;

    // A fragments (one-time): af[kc], lane holds row = m0 + w*16 + fr,
    // cols kc*32 + qr*8 .. +8
    short8 af[8];
#pragma unroll
    for (int kc = 0; kc < 8; kc++) {
        int row = m0 + w * 16 + fr;
        const float* p = flat + (size_t)row * DIN + kc * 32 + qr * 8;
        float4 a = *(const float4*)p;
        float4 b = *(const float4*)(p + 4);
        float f[8] = {a.x, a.y, a.z, a.w, b.x, b.y, b.z, b.w};
        unsigned short* hp = (unsigned short*)&af[kc];
#pragma unroll
        for (int j = 0; j < 8; j++) hp[j] = bf16rne(f[j]);
    }

    const unsigned short* __restrict__ Bbase = Bh + (size_t)lane * 8;
    // tile (kc, nt) at: Bbase + ((size_t)kc*NTB + nt)*512

    float bestv[4];
    int besti[4];
#pragma unroll
    for (int r = 0; r < 4; r++) { bestv[r] = -3.4e38f; besti[r] = 0; }

    const f32x4 ZERO4 = {0.f, 0.f, 0.f, 0.f};

    short8 bf[8];
    // prologue: load nt=0 tiles
#pragma unroll
    for (int kc = 0; kc < 8; kc++)
        bf[kc] = *(const short8*)(Bbase + ((size_t)kc * NTB) * 512);

#pragma unroll 1
    for (int nt = 0; nt < 128; nt++) {
        f32x4 acc;
        // kc = 0: C = 0 operand (same chain as prior rounds -> bit-exact)
        acc = __builtin_amdgcn_mfma_f32_16x16x32_bf16(af[0], bf[0], ZERO4, 0, 0, 0);
#pragma unroll
        for (int kc = 1; kc < 4; kc++)
            acc = __builtin_amdgcn_mfma_f32_16x16x32_bf16(af[kc], bf[kc], acc, 0, 0, 0);
        // reload bf[0..3] for nt+1 (hides L2 latency under remaining MFMAs)
        if (nt < 127) {
#pragma unroll
            for (int kc = 0; kc < 4; kc++)
                bf[kc] = *(const short8*)(Bbase + ((size_t)kc * NTB + nt + 1) * 512);
        }
#pragma unroll
        for (int kc = 4; kc < 8; kc++)
            acc = __builtin_amdgcn_mfma_f32_16x16x32_bf16(af[kc], bf[kc], acc, 0, 0, 0);
        if (nt < 127) {
#pragma unroll
            for (int kc = 4; kc < 8; kc++)
                bf[kc] = *(const short8*)(Bbase + ((size_t)kc * NTB + nt + 1) * 512);
        }
        // epilogue: codes nt*16 + fr
        const int base = nt * 16 + fr;
        const float cpv = cp[base];
#pragma unroll
        for (int r = 0; r < 4; r++) {
            float v = acc[r] + cpv;
            if (v > bestv[r]) { bestv[r] = v; besti[r] = base; }  // asc nt: ties -> lower
        }
    }

    // cross-fr argmax reduce (within 16-lane groups), tie -> lower idx.
    // After the xor butterfly, ALL lanes of each 16-group hold the result.
#pragma unroll
    for (int r = 0; r < 4; r++) {
        float bv = bestv[r];
        int bc = besti[r];
#pragma unroll
        for (int xm = 1; xm < 16; xm <<= 1) {
            float ov = __shfl_xor(bv, xm, 64);
            int oc = __shfl_xor(bc, xm, 64);
            if (ov > bv || (ov == bv && oc < bc)) { bv = ov; bc = oc; }
        }
        besti[r] = bc;
    }

    // fused gather: wave handles its own 16 rows; k broadcast via static shfl
    float lsum = 0.0f;
#pragma unroll
    for (int rq = 0; rq < 4; rq++) {
#pragma unroll
        for (int r = 0; r < 4; r++) {
            int rr = rq * 4 + r;
            int row = m0 + w * 16 + rr;
            int k = __shfl(besti[r], rq * 16, 64);      // row rr's argmax (uniform)
            const float* qr_ = Q + (size_t)k * DIN;
            const float* xr = flat + (size_t)row * DIN;
            float* ob = out + 1 + (size_t)row * DIN;
#pragma unroll
            for (int cc = 0; cc < 4; cc++) {
                int j = lane + 64 * cc;
                float q = qr_[j];
                float d = q - xr[j];
                lsum += d * d;
                ob[j] = q;
            }
            if (lane == 0) atomicAdd(out + 1 + TOK * DIN + k, 1.0f / (float)TOK);
        }
    }
#pragma unroll
    for (int off = 32; off; off >>= 1) lsum += __shfl_down(lsum, off, 64);
    if (lane == 0) atomicAdd(out, lsum * (1.25f / (float)((size_t)TOK * DIN)));
}

extern "C" void kernel_launch(void* const* d_in, const int* in_sizes, int n_in,
                              void* d_out, int out_size, void* d_ws, size_t ws_size,
                              hipStream_t stream) {
    const float* inputs = (const float*)d_in[0];
    const float* bn1_gamma = (const float*)d_in[1];
    const float* bn1_beta  = (const float*)d_in[2];
    const float* W1 = (const float*)d_in[3];
    const float* b1 = (const float*)d_in[4];
    const float* E  = (const float*)d_in[5];
    const float* bn2_gamma = (const float*)d_in[6];
    const float* bn2_beta  = (const float*)d_in[7];
    const float* W2 = (const float*)d_in[8];
    const float* b2 = (const float*)d_in[9];

    float* ws = (float*)d_ws;
    float* cp  = ws + OFF_CP;
    float* Q   = ws + OFF_Q;
    float* W2T = ws + OFF_W2T;
    float* u   = ws + OFF_U;
    float* cQ  = ws + OFF_CQ;
    unsigned short* Bh = (unsigned short*)(ws + OFF_BH);
    float* out = (float*)d_out;

    hipLaunchKernelGGL(prep1_kernel, dim3(768), dim3(256), 0, stream,
                       W1, W2, bn1_beta, bn2_gamma, bn2_beta, b2, W2T, u, cQ, out);
    hipLaunchKernelGGL(prep2_kernel, dim3(256), dim3(512), 0, stream,
                       E, W1, W2T, bn1_gamma, cQ, b1, u, Q, cp, Bh);
    hipLaunchKernelGGL(score_fused_kernel, dim3(1024), dim3(256), 0, stream,
                       inputs, Bh, cp, Q, out);
}

// Round 8
// 339.517 us; speedup vs baseline: 1.0447x; 1.0447x over previous
//
#include <hip/hip_runtime.h>
#include <math.h>
#include <stdint.h>

#define TOK 65536
#define DIN 256
#define EDIM 512
#define KCB 2048
#define NTB 128         // B n-tiles (2048/16)

// workspace layout (float offsets), 64-float aligned
#define OFF_KSEL 0u                     // ksel [65536] ints (in old Mp space)
#define OFF_CP   524288u                // c' [2048]
#define OFF_Q    526336u                // Q [2048*256]
#define OFF_W2T  1050624u               // W2T [512*256]
#define OFF_U    1181696u               // u [512]
#define OFF_CQ   1182208u               // cQ [256]
#define OFF_BH   1182464u               // B packed bf16 [8][128][512]
#define TOT_F    1444608u

typedef short short8 __attribute__((ext_vector_type(8)));
typedef float f32x4 __attribute__((ext_vector_type(4)));

__device__ __forceinline__ unsigned short bf16rne(float x) {
    uint32_t u = __float_as_uint(x);
    u += 0x7fffu + ((u >> 16) & 1u);
    return (unsigned short)(u >> 16);
}

// fused: zero loss scalar + usage bins, then W2T / u / cQ.
// blocks 0..511: e -> W2T[e][o], u[e];  512..767: o -> cQ[o]
__global__ void prep1_kernel(const float* __restrict__ W1, const float* __restrict__ W2,
                             const float* __restrict__ bn1_beta, const float* __restrict__ bn2_gamma,
                             const float* __restrict__ bn2_beta, const float* __restrict__ b2,
                             float* __restrict__ W2T, float* __restrict__ u, float* __restrict__ cQ,
                             float* __restrict__ out) {
    __shared__ float red[256];
    const int b = blockIdx.x, t = threadIdx.x;
    const int gid = b * 256 + t;
    if (gid == 0) out[0] = 0.0f;
    if (gid < KCB) out[1 + TOK * DIN + gid] = 0.0f;
    const float s = 1.0f / sqrtf(1.0f + 1e-5f);
    if (b < EDIM) {
        int e = b;
        W2T[e * DIN + t] = bn2_gamma[e] * s * W2[t * EDIM + e];
        float v = bn1_beta[t] * W1[e * DIN + t];
        red[t] = v; __syncthreads();
        for (int off = 128; off; off >>= 1) { if (t < off) red[t] += red[t + off]; __syncthreads(); }
        if (t == 0) u[e] = red[0];
    } else {
        int o = b - EDIM;
        float v = bn2_beta[t] * W2[o * EDIM + t] + bn2_beta[t + 256] * W2[o * EDIM + t + 256];
        red[t] = v; __syncthreads();
        for (int off = 128; off; off >>= 1) { if (t < off) red[t] += red[t + off]; __syncthreads(); }
        if (t == 0) cQ[o] = b2[o] + red[0];
    }
}

// FUSED prep2+packB: 256 blocks x 512 threads; 8 codebook rows per block
// (half h = t>>8 owns rows h*4..h*4+3, col = t&255).
// Broadcast operand E read via wave-uniform SCALAR loads (SMEM path).
// Outputs: Q (fp32), cp, and Bh bf16 MFMA fragments DIRECTLY.
__global__ __launch_bounds__(512) void prep2_kernel(const float* __restrict__ E, const float* __restrict__ W1,
                                                    const float* __restrict__ W2T, const float* __restrict__ bn1_gamma,
                                                    const float* __restrict__ cQ, const float* __restrict__ b1,
                                                    const float* __restrict__ u,
                                                    float* __restrict__ Q, float* __restrict__ cp,
                                                    unsigned short* __restrict__ Bh) {
    __shared__ __align__(16) unsigned short hs[8][264];   // bf16 of Mp rows, padded
    const int t = threadIdx.x;
    const int col = t & 255;
    const int half = __builtin_amdgcn_readfirstlane(t >> 8);   // wave-uniform 0/1
    const int k0 = blockIdx.x * 8;
    const float* __restrict__ Ek = E + ((size_t)k0 + (size_t)half * 4) * EDIM;

    float m[4] = {0, 0, 0, 0};
    float q[4] = {0, 0, 0, 0};
    for (int e0 = 0; e0 < EDIM; e0 += 8) {
        float w1v[8], w2v[8];
#pragma unroll
        for (int j = 0; j < 8; j++) {
            w1v[j] = W1[(e0 + j) * DIN + col];
            w2v[j] = W2T[(e0 + j) * DIN + col];
        }
#pragma unroll
        for (int r = 0; r < 4; r++) {
#pragma unroll
            for (int j = 0; j < 8; j++) {
                float ev = Ek[(size_t)r * EDIM + e0 + j];   // uniform -> s_load
                m[r] += ev * w1v[j];
                q[r] += ev * w2v[j];
            }
        }
    }
    const float s = 1.0f / sqrtf(1.0f + 1e-5f);
    const float gs = bn1_gamma[col] * s;
    const float cq = cQ[col];
#pragma unroll
    for (int r = 0; r < 4; r++) {
        Q[(size_t)(k0 + half * 4 + r) * DIN + col] = q[r] + cq;
        hs[half * 4 + r][col] = bf16rne(gs * m[r]);
    }

    // fused prep3: c'[k0+wv] = E[k]·(b1+u) - 0.5*||E[k]||², one wave per row
    {
        const int wv = t >> 6, l = t & 63;
        const float* __restrict__ Er = E + (size_t)(k0 + wv) * EDIM;
        float sa = 0.0f, sb = 0.0f;
#pragma unroll
        for (int i = 0; i < 8; i++) {
            int e = l + i * 64;
            float ev = Er[e];
            float be = b1[e] + u[e];
            sa += ev * be; sb += ev * ev;
        }
        float v = sa - 0.5f * sb;
#pragma unroll
        for (int off = 32; off; off >>= 1) v += __shfl_down(v, off, 64);
        if (l == 0) cp[k0 + wv] = v;
    }

    __syncthreads();   // hs complete

    // Bh fragment write: 256 chunks of 16B (8 rows x 8 kc x 4 qr), threads t<256.
    if (t < 256) {
        const int rr = t & 7, qr = (t >> 3) & 3, kc = t >> 5;
        const int nt = k0 >> 4;
        const int l2 = (k0 & 8) + rr + (qr << 4);
        short8 vh = *(const short8*)&hs[rr][kc * 32 + qr * 8];
        *(short8*)&Bh[((size_t)kc * NTB + nt) * 512 + (size_t)l2 * 8] = vh;
    }
}

// SCORER v8: R6's exact bit-chain (A-stationary streaming, no main-loop
// barriers) with (a) gather split OUT (writes ksel only), (b) depth-2 B
// prefetch: two-tile bfA/bfB rotation raises issue-to-use distance from
// ~0.7 tile (~150 cyc, < L2 latency -> per-iter stalls) to ~1.7 tiles
// (~700 cyc). Same MFMA order, cp add, compare ladder -> bit-exact argmax.
__global__ __launch_bounds__(256, 2) void score_kernel(const float* __restrict__ flat,
                                                       const unsigned short* __restrict__ Bh,
                                                       const float* __restrict__ cp,
                                                       int* __restrict__ ksel_g) {
    __shared__ float mv[2][128];
    __shared__ int   mi[2][128];
    const int t = threadIdx.x, lane = t & 63, w = t >> 6;
    const int wr = w >> 1, wc = w & 1;
    const int m0 = blockIdx.x * 128;
    const int fr = lane & 15, qr = lane >> 4;

    // A fragments from raw fp32 (one-time): af[kc][mt], lane holds
    // row = wr*64 + mt*16 + fr, cols kc*32 + qr*8 .. +8
    short8 af[8][4];
#pragma unroll
    for (int kc = 0; kc < 8; kc++)
#pragma unroll
        for (int mt = 0; mt < 4; mt++) {
            int row = m0 + wr * 64 + mt * 16 + fr;
            const float* p = flat + (size_t)row * DIN + kc * 32 + qr * 8;
            float4 a = *(const float4*)p;
            float4 b = *(const float4*)(p + 4);
            float f[8] = {a.x, a.y, a.z, a.w, b.x, b.y, b.z, b.w};
            unsigned short* hp = (unsigned short*)&af[kc][mt];
#pragma unroll
            for (int j = 0; j < 8; j++) hp[j] = bf16rne(f[j]);
        }

    // per-wave B stream base: code half wc (n-tiles wc*64 .. wc*64+63)
    const unsigned short* __restrict__ Bbase = Bh + ((size_t)(wc * 64)) * 512 + (size_t)lane * 8;

    float bestv[4][4];
    int besti[4][4];
#pragma unroll
    for (int mt = 0; mt < 4; mt++)
#pragma unroll
        for (int r = 0; r < 4; r++) { bestv[mt][r] = -3.4e38f; besti[mt][r] = 0; }

    const f32x4 ZERO4 = {0.f, 0.f, 0.f, 0.f};

#define LOADT(BUF, NTV)                                                              \
    do { _Pragma("unroll")                                                           \
        for (int kc_ = 0; kc_ < 8; kc_++)                                            \
            BUF[kc_] = *(const short8*)(Bbase + ((size_t)kc_ * NTB + (NTV)) * 512);  \
    } while (0)

#define DO_TILE(BUF, NTV)                                                            \
    do {                                                                             \
        f32x4 acc[4];                                                                \
        _Pragma("unroll")                                                            \
        for (int mt_ = 0; mt_ < 4; mt_++)                                            \
            acc[mt_] = __builtin_amdgcn_mfma_f32_16x16x32_bf16(af[0][mt_], BUF[0], ZERO4, 0, 0, 0); \
        _Pragma("unroll")                                                            \
        for (int kc_ = 1; kc_ < 8; kc_++) {                                          \
            _Pragma("unroll")                                                        \
            for (int mt_ = 0; mt_ < 4; mt_++)                                        \
                acc[mt_] = __builtin_amdgcn_mfma_f32_16x16x32_bf16(af[kc_][mt_], BUF[kc_], acc[mt_], 0, 0, 0); \
        }                                                                            \
        const int base_ = wc * 1024 + (NTV) * 16 + fr;                               \
        const float cpv_ = cp[base_];                                                \
        _Pragma("unroll")                                                            \
        for (int mt_ = 0; mt_ < 4; mt_++) {                                          \
            _Pragma("unroll")                                                        \
            for (int r_ = 0; r_ < 4; r_++) {                                         \
                float v_ = acc[mt_][r_] + cpv_;                                      \
                if (v_ > bestv[mt_][r_]) { bestv[mt_][r_] = v_; besti[mt_][r_] = base_; } \
            }                                                                        \
        }                                                                            \
    } while (0)

    short8 bfA[8], bfB[8];
    LOADT(bfA, 0);
    LOADT(bfB, 1);

#pragma unroll 1
    for (int nt = 0; nt < 64; nt += 2) {
        DO_TILE(bfA, nt);
        if (nt + 2 < 64) LOADT(bfA, nt + 2);     // used 2 tiles later
        DO_TILE(bfB, nt + 1);
        if (nt + 3 < 64) LOADT(bfB, nt + 3);
    }
#undef LOADT
#undef DO_TILE

    // cross-fr argmax reduce (within 16-lane groups), tie -> lower idx
#pragma unroll
    for (int mt = 0; mt < 4; mt++)
#pragma unroll
        for (int r = 0; r < 4; r++) {
            float bv = bestv[mt][r];
            int bc = besti[mt][r];
#pragma unroll
            for (int xm = 1; xm < 16; xm <<= 1) {
                float ov = __shfl_xor(bv, xm, 64);
                int oc = __shfl_xor(bc, xm, 64);
                if (ov > bv || (ov == bv && oc < bc)) { bv = ov; bc = oc; }
            }
            if (fr == 0) {
                int rl = wr * 64 + mt * 16 + qr * 4 + r;
                mv[wc][rl] = bv;
                mi[wc][rl] = bc;
            }
        }
    __syncthreads();

    // merge across wc (lex: v desc, idx asc) -> ksel
    if (t < 128) {
        float v0 = mv[0][t], v1 = mv[1][t];
        int c0 = mi[0][t], c1 = mi[1][t];
        ksel_g[m0 + t] = (v1 > v0 || (v1 == v0 && c1 < c0)) ? c1 : c0;
    }
}

// GATHER: streaming Q-gather + loss + usage + output. Block/wave/row mapping
// and per-row summation order identical to v6's fused tail -> same values.
__global__ __launch_bounds__(256) void gather_kernel(const float* __restrict__ flat,
                                                     const float* __restrict__ Q,
                                                     const int* __restrict__ ksel_g,
                                                     float* __restrict__ out) {
    const int t = threadIdx.x, lane = t & 63, w = t >> 6;
    const int m0 = blockIdx.x * 128;
    float lsum = 0.0f;
    for (int rr = 0; rr < 32; rr++) {
        int rl = w * 32 + rr;
        int row = m0 + rl;
        int k = ksel_g[row];                    // same-address broadcast
        const float* qr_ = Q + (size_t)k * DIN;
        const float* xr = flat + (size_t)row * DIN;
        float* ob = out + 1 + (size_t)row * DIN;
#pragma unroll
        for (int cc = 0; cc < 4; cc++) {
            int j = lane + 64 * cc;
            float q = qr_[j];
            float d = q - xr[j];
            lsum += d * d;
            ob[j] = q;
        }
        if (lane == 0) atomicAdd(out + 1 + TOK * DIN + k, 1.0f / (float)TOK);
    }
#pragma unroll
    for (int off = 32; off; off >>= 1) lsum += __shfl_down(lsum, off, 64);
    if (lane == 0) atomicAdd(out, lsum * (1.25f / (float)((size_t)TOK * DIN)));
}

extern "C" void kernel_launch(void* const* d_in, const int* in_sizes, int n_in,
                              void* d_out, int out_size, void* d_ws, size_t ws_size,
                              hipStream_t stream) {
    const float* inputs = (const float*)d_in[0];
    const float* bn1_gamma = (const float*)d_in[1];
    const float* bn1_beta  = (const float*)d_in[2];
    const float* W1 = (const float*)d_in[3];
    const float* b1 = (const float*)d_in[4];
    const float* E  = (const float*)d_in[5];
    const float* bn2_gamma = (const float*)d_in[6];
    const float* bn2_beta  = (const float*)d_in[7];
    const float* W2 = (const float*)d_in[8];
    const float* b2 = (const float*)d_in[9];

    float* ws = (float*)d_ws;
    int*   ksel = (int*)(ws + OFF_KSEL);
    float* cp  = ws + OFF_CP;
    float* Q   = ws + OFF_Q;
    float* W2T = ws + OFF_W2T;
    float* u   = ws + OFF_U;
    float* cQ  = ws + OFF_CQ;
    unsigned short* Bh = (unsigned short*)(ws + OFF_BH);
    float* out = (float*)d_out;

    hipLaunchKernelGGL(prep1_kernel, dim3(768), dim3(256), 0, stream,
                       W1, W2, bn1_beta, bn2_gamma, bn2_beta, b2, W2T, u, cQ, out);
    hipLaunchKernelGGL(prep2_kernel, dim3(256), dim3(512), 0, stream,
                       E, W1, W2T, bn1_gamma, cQ, b1, u, Q, cp, Bh);
    hipLaunchKernelGGL(score_kernel, dim3(512), dim3(256), 0, stream,
                       inputs, Bh, cp, ksel);
    hipLaunchKernelGGL(gather_kernel, dim3(512), dim3(256), 0, stream,
                       inputs, Q, ksel, out);
}